// Round 4
// baseline (94.073 us; speedup 1.0000x reference)
//
#include <hip/hip_runtime.h>
#include <math.h>

#define REG_COEF 25.0f
#define B 8
#define H 3
#define N 4096

static constexpr int NX = B * N;          // 32768 packed sample points
static constexpr int NY = B * H * N;      // 98304 packed reflected points
static constexpr int NM = 2 * B * H * N;  // 196608 per-query mins

// ws layout (float units):
//   [0, 131072)           : X packed float4 (x,y,z,|x|^2)   (32768 float4)
//   [131072, 524288)      : Y packed float4 (reflected + |y|^2) (98304 float4)
//   [524288, 720896)      : mins (196608 floats)

__global__ void prep_kernel(const float* __restrict__ pts, const float* __restrict__ ypred,
                            float4* __restrict__ X, float4* __restrict__ Y,
                            float* __restrict__ mins, float* __restrict__ out)
{
    int idx = blockIdx.x * blockDim.x + threadIdx.x;
    if (idx == 0) {
        float reg = 0.f;
        for (int b = 0; b < B; ++b) {
            float n[H][3];
            #pragma unroll
            for (int h = 0; h < H; ++h) {
                float a0 = ypred[b * 12 + h * 4 + 0];
                float a1 = ypred[b * 12 + h * 4 + 1];
                float a2 = ypred[b * 12 + h * 4 + 2];
                float inv = rsqrtf(a0 * a0 + a1 * a1 + a2 * a2);
                n[h][0] = a0 * inv; n[h][1] = a1 * inv; n[h][2] = a2 * inv;
            }
            float s = 0.f;
            #pragma unroll
            for (int c = 0; c < H; ++c)
                #pragma unroll
                for (int e = 0; e < H; ++e) {
                    float g = n[c][0] * n[e][0] + n[c][1] * n[e][1] + n[c][2] * n[e][2];
                    if (c == e) g -= 1.f;
                    s += g * g;
                }
            reg += sqrtf(s);
        }
        out[0] = REG_COEF * reg;   // reduce_kernel accumulates on top
    }

    if (idx < NX) {
        float x0 = pts[(size_t)idx * 3 + 0];
        float x1 = pts[(size_t)idx * 3 + 1];
        float x2 = pts[(size_t)idx * 3 + 2];
        X[idx] = make_float4(x0, x1, x2, x0 * x0 + x1 * x1 + x2 * x2);
    } else if (idx < NX + NY) {
        int t = idx - NX;            // (b*H + h)*N + nn
        int nn = t & (N - 1);
        int bh = t >> 12;
        int b = bh / H, h = bh - b * H;
        float a0 = ypred[b * 12 + h * 4 + 0];
        float a1 = ypred[b * 12 + h * 4 + 1];
        float a2 = ypred[b * 12 + h * 4 + 2];
        float off = ypred[b * 12 + h * 4 + 3];
        float inv = rsqrtf(a0 * a0 + a1 * a1 + a2 * a2);
        a0 *= inv; a1 *= inv; a2 *= inv;
        const float* p = pts + ((size_t)b * N + nn) * 3;
        float x0 = p[0], x1 = p[1], x2 = p[2];
        float dist = a0 * x0 + a1 * x1 + a2 * x2 + off;
        float y0 = fmaf(-2.f * dist, a0, x0);
        float y1 = fmaf(-2.f * dist, a1, x1);
        float y2 = fmaf(-2.f * dist, a2, x2);
        Y[t] = make_float4(y0, y1, y2, y0 * y0 + y1 * y1 + y2 * y2);
    } else if (idx < NX + NY + NM) {
        mins[idx - NX - NY] = __uint_as_float(0x7F800000u);  // +inf
    }
}

// 1536 blocks: [tslice(16)][qchunk(2)][h(3)][b(8)][dir(2)]
// 256 threads x Q=8 queries; targets read via wave-uniform address -> s_load
// (scalar cache), consumed as the SGPR operand of each v_fma. No LDS at all.
__global__ __launch_bounds__(256) void chamfer_kernel(const float4* __restrict__ X,
                                                      const float4* __restrict__ Y,
                                                      float* __restrict__ mins)
{
    int bid = blockIdx.x;
    int tslice = bid & 15;
    int qchunk = (bid >> 4) & 1;
    int rest = bid >> 5;        // 0..47
    int hh = rest % 3;
    int tmp = rest / 3;         // 0..15
    int b = tmp & 7;
    int dir = tmp >> 3;

    const float4* Xb = X + b * N;
    const float4* Yb = Y + (b * H + hh) * N;
    const float4* q;
    const float4* t;
    float* mb;
    if (dir == 0) { q = Xb; t = Yb; mb = mins + (b * H + hh) * N; }
    else          { q = Yb; t = Xb; mb = mins + B * H * N + (b * H + hh) * N; }
    q += qchunk * 2048;
    mb += qchunk * 2048;
    t += tslice * 256;

    int tid = threadIdx.x;

    // query regs: (-2x, -2y, -2z) and |q|^2
    float qx[8], qy[8], qz[8], qw[8], m[8];
    #pragma unroll
    for (int k = 0; k < 8; ++k) {
        float4 P = q[tid + 256 * k];
        qx[k] = -2.f * P.x; qy[k] = -2.f * P.y; qz[k] = -2.f * P.z;
        qw[k] = P.w; m[k] = INFINITY;
    }

    #pragma unroll 4
    for (int j = 0; j < 256; j += 2) {
        float4 Ta = t[j];       // wave-uniform -> s_load_dwordx4/x8
        float4 Tb = t[j + 1];
        #pragma unroll
        for (int k = 0; k < 8; ++k) {
            float va = fmaf(qx[k], Ta.x, fmaf(qy[k], Ta.y, fmaf(qz[k], Ta.z, Ta.w)));
            float vb = fmaf(qx[k], Tb.x, fmaf(qy[k], Tb.y, fmaf(qz[k], Tb.z, Tb.w)));
            m[k] = fminf(m[k], fminf(va, vb));   // -> v_min3_f32
        }
    }

    #pragma unroll
    for (int k = 0; k < 8; ++k) {
        float v = fmaxf(m[k] + qw[k], 0.f);  // + |q|^2, clamp for uint-min ordering
        atomicMin((unsigned int*)&mb[tid + 256 * k], __float_as_uint(v));
    }
}

__global__ void reduce_kernel(const float* __restrict__ mins, float* __restrict__ out)
{
    int tid = blockIdx.x * blockDim.x + threadIdx.x;  // 192*256 = 49152 threads
    float s = 0.f;
    #pragma unroll
    for (int k = 0; k < 4; ++k) s += mins[tid + k * 49152];
    #pragma unroll
    for (int off = 32; off > 0; off >>= 1) s += __shfl_down(s, off);
    if ((threadIdx.x & 63) == 0) atomicAdd(out, s);
}

extern "C" void kernel_launch(void* const* d_in, const int* in_sizes, int n_in,
                              void* d_out, int out_size, void* d_ws, size_t ws_size,
                              hipStream_t stream)
{
    const float* pts = (const float*)d_in[0];   // (8,4096,3) fp32
    const float* yp  = (const float*)d_in[1];   // (8,3,4) fp32
    float* out = (float*)d_out;
    float* ws  = (float*)d_ws;

    float4* X = (float4*)ws;                    // 32768 float4
    float4* Y = (float4*)(ws + 131072);         // 98304 float4
    float* mins = ws + 524288;                  // 196608 floats

    prep_kernel<<<896, 256, 0, stream>>>(pts, yp, X, Y, mins, out);
    chamfer_kernel<<<1536, 256, 0, stream>>>(X, Y, mins);
    reduce_kernel<<<192, 256, 0, stream>>>(mins, out);
}

// Round 5
// 81.979 us; speedup vs baseline: 1.1475x; 1.1475x over previous
//
#include <hip/hip_runtime.h>
#include <math.h>

#define REG_COEF 25.0f
#define B 8
#define H 3
#define N 4096

typedef float f2 __attribute__((ext_vector_type(2)));
typedef float f4 __attribute__((ext_vector_type(4)));

static constexpr int NX = B * N;          // 32768 sample points
static constexpr int NY = B * H * N;      // 98304 reflected points
static constexpr int NM = 2 * B * H * N;  // 196608 per-query mins

// Pair-interleaved SoA ("pk") layout: for point pair g (points 2g, 2g+1):
//   pk[g*8 + 0,1] = x0,x1 ; +2,3 = y0,y1 ; +4,5 = z0,z1 ; +6,7 = |p|^2 pair
// ws layout (float units):
//   [0, 131072)           : Xpk   (16384 pairs)
//   [131072, 524288)      : Ypk   (49152 pairs)
//   [524288, 720896)      : mins  (196608 floats)

__global__ void prep_kernel(const float* __restrict__ pts, const float* __restrict__ ypred,
                            float* __restrict__ Xpk, float* __restrict__ Ypk,
                            float* __restrict__ mins, float* __restrict__ out)
{
    int idx = blockIdx.x * blockDim.x + threadIdx.x;
    if (idx == 0) {
        float reg = 0.f;
        for (int b = 0; b < B; ++b) {
            float n[H][3];
            #pragma unroll
            for (int h = 0; h < H; ++h) {
                float a0 = ypred[b * 12 + h * 4 + 0];
                float a1 = ypred[b * 12 + h * 4 + 1];
                float a2 = ypred[b * 12 + h * 4 + 2];
                float inv = rsqrtf(a0 * a0 + a1 * a1 + a2 * a2);
                n[h][0] = a0 * inv; n[h][1] = a1 * inv; n[h][2] = a2 * inv;
            }
            float s = 0.f;
            #pragma unroll
            for (int c = 0; c < H; ++c)
                #pragma unroll
                for (int e = 0; e < H; ++e) {
                    float g = n[c][0] * n[e][0] + n[c][1] * n[e][1] + n[c][2] * n[e][2];
                    if (c == e) g -= 1.f;
                    s += g * g;
                }
            reg += sqrtf(s);
        }
        out[0] = REG_COEF * reg;   // reduce_kernel accumulates on top
    }

    if (idx < NX / 2) {
        // X pair g = idx: points 2g, 2g+1
        const float* p = pts + (size_t)idx * 6;
        float x0 = p[0], y0 = p[1], z0 = p[2];
        float x1 = p[3], y1 = p[4], z1 = p[5];
        f4* dst = (f4*)(Xpk + (size_t)idx * 8);
        dst[0] = (f4){x0, x1, y0, y1};
        dst[1] = (f4){z0, z1,
                      x0 * x0 + y0 * y0 + z0 * z0,
                      x1 * x1 + y1 * y1 + z1 * z1};
    } else if (idx < NX / 2 + NY / 2) {
        int g = idx - NX / 2;           // Y pair index
        int t0 = 2 * g;                 // point index (b*H+h)*N + nn
        int nn = t0 & (N - 1);
        int bh = t0 >> 12;
        int b = bh / H, h = bh - b * H;
        float a0 = ypred[b * 12 + h * 4 + 0];
        float a1 = ypred[b * 12 + h * 4 + 1];
        float a2 = ypred[b * 12 + h * 4 + 2];
        float off = ypred[b * 12 + h * 4 + 3];
        float inv = rsqrtf(a0 * a0 + a1 * a1 + a2 * a2);
        a0 *= inv; a1 *= inv; a2 *= inv;
        const float* p = pts + ((size_t)b * N + nn) * 3;
        float u0 = p[0], u1 = p[1], u2 = p[2];
        float v0 = p[3], v1 = p[4], v2 = p[5];
        float d0 = a0 * u0 + a1 * u1 + a2 * u2 + off;
        float d1 = a0 * v0 + a1 * v1 + a2 * v2 + off;
        float x0 = fmaf(-2.f * d0, a0, u0), y0 = fmaf(-2.f * d0, a1, u1), z0 = fmaf(-2.f * d0, a2, u2);
        float x1 = fmaf(-2.f * d1, a0, v0), y1 = fmaf(-2.f * d1, a1, v1), z1 = fmaf(-2.f * d1, a2, v2);
        f4* dst = (f4*)(Ypk + (size_t)g * 8);
        dst[0] = (f4){x0, x1, y0, y1};
        dst[1] = (f4){z0, z1,
                      x0 * x0 + y0 * y0 + z0 * z0,
                      x1 * x1 + y1 * y1 + z1 * z1};
    } else if (idx < NX / 2 + NY / 2 + NM) {
        mins[idx - NX / 2 - NY / 2] = __uint_as_float(0x7F800000u);  // +inf
    }
}

// 1536 blocks: [tslice(16)][qchunk(2)][h(3)][b(8)][dir(2)]
// 256 threads x Q=8 queries, 256 targets (128 pk groups) staged in LDS.
// Inner op: v_pk_fma_f32 on target pairs -> 2.0 VALU instr per (q,t) pair.
__global__ __launch_bounds__(256) void chamfer_kernel(const float* __restrict__ Xpk,
                                                      const float* __restrict__ Ypk,
                                                      float* __restrict__ mins)
{
    __shared__ f4 tile[256];            // 128 pk groups
    int bid = blockIdx.x;
    int tslice = bid & 15;
    int qchunk = (bid >> 4) & 1;
    int rest = bid >> 5;        // 0..47
    int hh = rest % 3;
    int tmp = rest / 3;         // 0..15
    int b = tmp & 7;
    int dir = tmp >> 3;

    const float* Qpk;
    const float* Tpk;
    float* mb;
    if (dir == 0) {
        Qpk = Xpk + (size_t)b * 16384;
        Tpk = Ypk + (size_t)(b * H + hh) * 16384;
        mb = mins + (b * H + hh) * N;
    } else {
        Qpk = Ypk + (size_t)(b * H + hh) * 16384;
        Tpk = Xpk + (size_t)b * 16384;
        mb = mins + B * H * N + (b * H + hh) * N;
    }
    Qpk += qchunk * 8192;      // 2048 points = 1024 pairs = 8192 floats
    mb  += qchunk * 2048;
    Tpk += tslice * 1024;      // 256 points = 128 pairs = 1024 floats

    int tid = threadIdx.x;
    tile[tid] = ((const f4*)Tpk)[tid];
    __syncthreads();

    // query regs: packed (-2x,-2x), (-2y,-2y), (-2z,-2z), plus |q|^2 and min
    f2 qx[8], qy[8], qz[8];
    float qw[8], m[8];
    #pragma unroll
    for (int k = 0; k < 8; ++k) {
        int i = tid + 256 * k;
        const float* qp = Qpk + (size_t)(i >> 1) * 8 + (i & 1);
        float ax = -2.f * qp[0], ay = -2.f * qp[2], az = -2.f * qp[4];
        qx[k] = (f2){ax, ax}; qy[k] = (f2){ay, ay}; qz[k] = (f2){az, az};
        qw[k] = qp[6]; m[k] = INFINITY;
    }

    #pragma unroll 2
    for (int g = 0; g < 128; ++g) {
        f4 u = tile[2 * g];        // x0 x1 y0 y1
        f4 w = tile[2 * g + 1];    // z0 z1 w0 w1
        f2 Txx = u.xy, Tyy = u.zw, Tzz = w.xy, Tww = w.zw;
        #pragma unroll
        for (int k = 0; k < 8; ++k) {
            f2 acc = __builtin_elementwise_fma(qx[k], Txx,
                     __builtin_elementwise_fma(qy[k], Tyy,
                     __builtin_elementwise_fma(qz[k], Tzz, Tww)));
            m[k] = fminf(m[k], fminf(acc.x, acc.y));   // -> v_min3_f32
        }
    }

    #pragma unroll
    for (int k = 0; k < 8; ++k) {
        float v = fmaxf(m[k] + qw[k], 0.f);  // + |q|^2, clamp for uint-min ordering
        atomicMin((unsigned int*)&mb[tid + 256 * k], __float_as_uint(v));
    }
}

__global__ void reduce_kernel(const float* __restrict__ mins, float* __restrict__ out)
{
    int tid = blockIdx.x * blockDim.x + threadIdx.x;  // 192*256 = 49152 threads
    float s = 0.f;
    #pragma unroll
    for (int k = 0; k < 4; ++k) s += mins[tid + k * 49152];
    #pragma unroll
    for (int off = 32; off > 0; off >>= 1) s += __shfl_down(s, off);
    if ((threadIdx.x & 63) == 0) atomicAdd(out, s);
}

extern "C" void kernel_launch(void* const* d_in, const int* in_sizes, int n_in,
                              void* d_out, int out_size, void* d_ws, size_t ws_size,
                              hipStream_t stream)
{
    const float* pts = (const float*)d_in[0];   // (8,4096,3) fp32
    const float* yp  = (const float*)d_in[1];   // (8,3,4) fp32
    float* out = (float*)d_out;
    float* ws  = (float*)d_ws;

    float* Xpk = ws;                            // 131072 floats
    float* Ypk = ws + 131072;                   // 393216 floats
    float* mins = ws + 524288;                  // 196608 floats

    prep_kernel<<<1024, 256, 0, stream>>>(pts, yp, Xpk, Ypk, mins, out);
    chamfer_kernel<<<1536, 256, 0, stream>>>(Xpk, Ypk, mins);
    reduce_kernel<<<192, 256, 0, stream>>>(mins, out);
}

// Round 6
// 80.804 us; speedup vs baseline: 1.1642x; 1.0145x over previous
//
#include <hip/hip_runtime.h>
#include <math.h>

#define REG_COEF 25.0f
#define B 8
#define H 3
#define N 4096

static constexpr int NX = B * N;          // 32768 packed sample points
static constexpr int NY = B * H * N;      // 98304 packed reflected points
static constexpr int NM = 2 * B * H * N;  // 196608 per-query mins

// ws layout (float units):
//   [0, 131072)           : X packed float4 (x,y,z,|x|^2)   (32768 float4)
//   [131072, 524288)      : Y packed float4 (reflected + |y|^2) (98304 float4)
//   [524288, 720896)      : mins (196608 floats)

__global__ void prep_kernel(const float* __restrict__ pts, const float* __restrict__ ypred,
                            float4* __restrict__ X, float4* __restrict__ Y,
                            float* __restrict__ mins, float* __restrict__ out)
{
    int idx = blockIdx.x * blockDim.x + threadIdx.x;
    if (idx == 0) {
        float reg = 0.f;
        for (int b = 0; b < B; ++b) {
            float n[H][3];
            #pragma unroll
            for (int h = 0; h < H; ++h) {
                float a0 = ypred[b * 12 + h * 4 + 0];
                float a1 = ypred[b * 12 + h * 4 + 1];
                float a2 = ypred[b * 12 + h * 4 + 2];
                float inv = rsqrtf(a0 * a0 + a1 * a1 + a2 * a2);
                n[h][0] = a0 * inv; n[h][1] = a1 * inv; n[h][2] = a2 * inv;
            }
            float s = 0.f;
            #pragma unroll
            for (int c = 0; c < H; ++c)
                #pragma unroll
                for (int e = 0; e < H; ++e) {
                    float g = n[c][0] * n[e][0] + n[c][1] * n[e][1] + n[c][2] * n[e][2];
                    if (c == e) g -= 1.f;
                    s += g * g;
                }
            reg += sqrtf(s);
        }
        out[0] = REG_COEF * reg;   // reduce_kernel accumulates on top
    }

    if (idx < NX) {
        float x0 = pts[(size_t)idx * 3 + 0];
        float x1 = pts[(size_t)idx * 3 + 1];
        float x2 = pts[(size_t)idx * 3 + 2];
        X[idx] = make_float4(x0, x1, x2, x0 * x0 + x1 * x1 + x2 * x2);
    } else if (idx < NX + NY) {
        int t = idx - NX;            // (b*H + h)*N + nn
        int nn = t & (N - 1);
        int bh = t >> 12;
        int b = bh / H, h = bh - b * H;
        float a0 = ypred[b * 12 + h * 4 + 0];
        float a1 = ypred[b * 12 + h * 4 + 1];
        float a2 = ypred[b * 12 + h * 4 + 2];
        float off = ypred[b * 12 + h * 4 + 3];
        float inv = rsqrtf(a0 * a0 + a1 * a1 + a2 * a2);
        a0 *= inv; a1 *= inv; a2 *= inv;
        const float* p = pts + ((size_t)b * N + nn) * 3;
        float x0 = p[0], x1 = p[1], x2 = p[2];
        float dist = a0 * x0 + a1 * x1 + a2 * x2 + off;
        float y0 = fmaf(-2.f * dist, a0, x0);
        float y1 = fmaf(-2.f * dist, a1, x1);
        float y2 = fmaf(-2.f * dist, a2, x2);
        Y[t] = make_float4(y0, y1, y2, y0 * y0 + y1 * y1 + y2 * y2);
    } else if (idx < NX + NY + NM) {
        mins[idx - NX - NY] = __uint_as_float(0x7F800000u);  // +inf
    }
}

// 1536 blocks: [tslice(32)][h(3)][b(8)][dir(2)]
// each block: 256 threads x Q=16 register-resident queries, scans a
// 128-target tile staged in LDS. 16 independent fma/min3 chains per thread
// hide VALU latency; 4 targets per group -> 2 chained v_min3.
__global__ __launch_bounds__(256, 4) void chamfer_kernel(const float4* __restrict__ X,
                                                         const float4* __restrict__ Y,
                                                         float* __restrict__ mins)
{
    __shared__ float4 tile[128];
    int bid = blockIdx.x;
    int tslice = bid & 31;
    int rest = bid >> 5;        // 0..47
    int hh = rest % 3;
    int tmp = rest / 3;         // 0..15
    int b = tmp & 7;
    int dir = tmp >> 3;

    const float4* Xb = X + b * N;
    const float4* Yb = Y + (b * H + hh) * N;
    const float4* q;
    const float4* t;
    float* mb;
    if (dir == 0) { q = Xb; t = Yb; mb = mins + (b * H + hh) * N; }
    else          { q = Yb; t = Xb; mb = mins + B * H * N + (b * H + hh) * N; }
    t += tslice * 128;

    int tid = threadIdx.x;
    if (tid < 128) tile[tid] = t[tid];
    __syncthreads();

    // query regs: (-2x, -2y, -2z), |q|^2, running min  (16 chains)
    float qx[16], qy[16], qz[16], qw[16], m[16];
    #pragma unroll
    for (int k = 0; k < 16; ++k) {
        float4 P = q[tid + 256 * k];
        qx[k] = -2.f * P.x; qy[k] = -2.f * P.y; qz[k] = -2.f * P.z;
        qw[k] = P.w; m[k] = INFINITY;
    }

    #pragma unroll 2
    for (int g = 0; g < 128; g += 4) {
        float4 T0 = tile[g];
        float4 T1 = tile[g + 1];
        float4 T2 = tile[g + 2];
        float4 T3 = tile[g + 3];
        #pragma unroll
        for (int k = 0; k < 16; ++k) {
            float v0 = fmaf(qx[k], T0.x, fmaf(qy[k], T0.y, fmaf(qz[k], T0.z, T0.w)));
            float v1 = fmaf(qx[k], T1.x, fmaf(qy[k], T1.y, fmaf(qz[k], T1.z, T1.w)));
            float v2 = fmaf(qx[k], T2.x, fmaf(qy[k], T2.y, fmaf(qz[k], T2.z, T2.w)));
            float v3 = fmaf(qx[k], T3.x, fmaf(qy[k], T3.y, fmaf(qz[k], T3.z, T3.w)));
            m[k] = fminf(fminf(m[k], v0), v1);   // -> v_min3_f32
            m[k] = fminf(fminf(m[k], v2), v3);   // -> v_min3_f32
        }
    }

    #pragma unroll
    for (int k = 0; k < 16; ++k) {
        float v = fmaxf(m[k] + qw[k], 0.f);  // + |q|^2, clamp for uint-min ordering
        atomicMin((unsigned int*)&mb[tid + 256 * k], __float_as_uint(v));
    }
}

__global__ void reduce_kernel(const float* __restrict__ mins, float* __restrict__ out)
{
    int tid = blockIdx.x * blockDim.x + threadIdx.x;  // 192*256 = 49152 threads
    float s = 0.f;
    #pragma unroll
    for (int k = 0; k < 4; ++k) s += mins[tid + k * 49152];
    #pragma unroll
    for (int off = 32; off > 0; off >>= 1) s += __shfl_down(s, off);
    if ((threadIdx.x & 63) == 0) atomicAdd(out, s);
}

extern "C" void kernel_launch(void* const* d_in, const int* in_sizes, int n_in,
                              void* d_out, int out_size, void* d_ws, size_t ws_size,
                              hipStream_t stream)
{
    const float* pts = (const float*)d_in[0];   // (8,4096,3) fp32
    const float* yp  = (const float*)d_in[1];   // (8,3,4) fp32
    float* out = (float*)d_out;
    float* ws  = (float*)d_ws;

    float4* X = (float4*)ws;                    // 32768 float4
    float4* Y = (float4*)(ws + 131072);         // 98304 float4
    float* mins = ws + 524288;                  // 196608 floats

    prep_kernel<<<1280, 256, 0, stream>>>(pts, yp, X, Y, mins, out);
    chamfer_kernel<<<1536, 256, 0, stream>>>(X, Y, mins);
    reduce_kernel<<<192, 256, 0, stream>>>(mins, out);
}